// Round 2
// baseline (9301.389 us; speedup 1.0000x reference)
//
#include <hip/hip_runtime.h>

#define DIM 64

// ---------------------------------------------------------------------------
// deg count: deg[col[e]] += 1  (float atomics; counts < 2^24 so exact)
// ---------------------------------------------------------------------------
__global__ void count_deg_kernel(const int* __restrict__ col,
                                 float* __restrict__ deg, int E) {
    int e = blockIdx.x * blockDim.x + threadIdx.x;
    if (e < E) atomicAdd(&deg[col[e]], 1.0f);
}

// dinv[i] = rsqrt(deg[i] + 1)   (+1 = self loop; always > 0)
__global__ void dinv_kernel(float* __restrict__ deg, int N) {
    int i = blockIdx.x * blockDim.x + threadIdx.x;
    if (i < N) deg[i] = rsqrtf(deg[i] + 1.0f);
}

// ---------------------------------------------------------------------------
// out[n][:] = dinv[n]^2 * in[n][:]   (self-loop term; also zero-inits out)
// one thread per float4 => t in [0, N*16)
// ---------------------------------------------------------------------------
__global__ void selfloop_init_kernel(const float* __restrict__ in,
                                     const float* __restrict__ dinv,
                                     float* __restrict__ out, int N) {
    int t = blockIdx.x * blockDim.x + threadIdx.x;
    if (t < N * (DIM / 4)) {
        int n = t >> 4;
        float d = dinv[n];
        d *= d;
        float4 v = ((const float4*)in)[t];
        v.x *= d; v.y *= d; v.z *= d; v.w *= d;
        ((float4*)out)[t] = v;
    }
}

// ---------------------------------------------------------------------------
// edge scatter: out[col[e]][:] += dinv[row]*dinv[col] * in[row[e]][:]
// 16 lanes per edge, each lane handles 4 consecutive dims (float4 gather,
// 4 scalar fp32 atomicAdds).
// ---------------------------------------------------------------------------
__global__ void scatter_kernel(const int* __restrict__ row,
                               const int* __restrict__ col,
                               const float* __restrict__ dinv,
                               const float* __restrict__ in,
                               float* __restrict__ out, int E) {
    int t = blockIdx.x * blockDim.x + threadIdx.x;
    int e = t >> 4;
    int l = t & 15;
    if (e < E) {
        int r = row[e];
        int c = col[e];
        float w = dinv[r] * dinv[c];
        float4 v = ((const float4*)(in + (size_t)r * DIM))[l];
        float* o = out + (size_t)c * DIM + l * 4;
        atomicAdd(o + 0, w * v.x);
        atomicAdd(o + 1, w * v.y);
        atomicAdd(o + 2, w * v.z);
        atomicAdd(o + 3, w * v.w);
    }
}

// ---------------------------------------------------------------------------
// Reference quirk: r never updates, so powers are cumulative:
//   x_agg[1] = A x, x_agg[2] = A^3 x, x_agg[4] = A^7 x.
// Fold the 6-channel concat into 4 effective 64x64 matrices:
//   cat@W = x@W3 + p1@(W0-W3+W4) + p3@(W1-W4+W5) + p7@(W2-W5)
// weff layout: [src][k][d], src: 0=x 1=A^1 2=A^3 3=A^7
// ---------------------------------------------------------------------------
__global__ void make_weff_kernel(const float* __restrict__ W,
                                 float* __restrict__ weff) {
    int t = blockIdx.x * blockDim.x + threadIdx.x;
    if (t < 64 * 64) {
        int k = t >> 6, d = t & 63;
        float w0 = W[(0 * 64 + k) * 64 + d];
        float w1 = W[(1 * 64 + k) * 64 + d];
        float w2 = W[(2 * 64 + k) * 64 + d];
        float w3 = W[(3 * 64 + k) * 64 + d];
        float w4 = W[(4 * 64 + k) * 64 + d];
        float w5 = W[(5 * 64 + k) * 64 + d];
        weff[(0 * 64 + k) * 64 + d] = w3;
        weff[(1 * 64 + k) * 64 + d] = w0 - w3 + w4;
        weff[(2 * 64 + k) * 64 + d] = w1 - w4 + w5;
        weff[(3 * 64 + k) * 64 + d] = w2 - w5;
    }
}

// ---------------------------------------------------------------------------
// combine: out[n][d] = relu(b[d] + sum_s sum_k in_s[n][k] * weff[s][k][d])
// Block: 256 threads, 16 nodes per iteration; thread owns (node = tid>>4,
// d4 = (tid&15)*4). Weff (64 KB) + staged inputs (16 KB) in LDS = 80 KB.
// Grid-stride over node groups.
// ---------------------------------------------------------------------------
__launch_bounds__(256)
__global__ void combine_kernel(const float* __restrict__ x,
                               const float* __restrict__ p1,
                               const float* __restrict__ p3,
                               const float* __restrict__ p7,
                               const float* __restrict__ weff,
                               const float* __restrict__ bias,
                               float* __restrict__ out, int N) {
    __shared__ float sW[4 * 64 * 64];   // [s][k][d]  64 KB
    __shared__ float sIn[16][4 * 64];   // [node][s*64+k] 16 KB

    int tid = threadIdx.x;
    for (int i = tid; i < 4 * 64 * 64; i += 256) sW[i] = weff[i];

    int node = tid >> 4;
    int d4 = (tid & 15) * 4;
    float4 bvec = *(const float4*)(bias + d4);

    int ngroups = (N + 15) / 16;
    for (int g = blockIdx.x; g < ngroups; g += gridDim.x) {
        int n0 = g * 16;
        __syncthreads();
        // stage 16 nodes x 4 sources x 64 dims = 1024 float4s
        for (int i = tid; i < 16 * 4 * 16; i += 256) {
            int nd = i >> 6;            // node
            int rem = i & 63;
            int src = rem >> 4;
            int f = rem & 15;
            int n = n0 + nd;
            float4 v = make_float4(0.f, 0.f, 0.f, 0.f);
            if (n < N) {
                const float* p = (src == 0) ? x : (src == 1) ? p1
                               : (src == 2) ? p3 : p7;
                v = *(const float4*)(p + (size_t)n * DIM + f * 4);
            }
            ((float4*)sIn[nd])[src * 16 + f] = v;
        }
        __syncthreads();

        float4 acc = bvec;
        #pragma unroll
        for (int s = 0; s < 4; ++s) {
            const float* ip = &sIn[node][s * 64];
            const float* wp = &sW[s * 4096 + d4];
            #pragma unroll 16
            for (int k = 0; k < 64; ++k) {
                float a = ip[k];
                float4 w = *(const float4*)(wp + k * 64);
                acc.x += a * w.x;
                acc.y += a * w.y;
                acc.z += a * w.z;
                acc.w += a * w.w;
            }
        }
        int n = n0 + node;
        if (n < N) {
            float4 r;
            r.x = fmaxf(acc.x, 0.f);
            r.y = fmaxf(acc.y, 0.f);
            r.z = fmaxf(acc.z, 0.f);
            r.w = fmaxf(acc.w, 0.f);
            *(float4*)(out + (size_t)n * DIM + d4) = r;
        }
    }
}

extern "C" void kernel_launch(void* const* d_in, const int* in_sizes, int n_in,
                              void* d_out, int out_size, void* d_ws, size_t ws_size,
                              hipStream_t stream) {
    const float* x  = (const float*)d_in[0];
    const int*   ei = (const int*)d_in[1];
    const float* W  = (const float*)d_in[2];
    const float* b  = (const float*)d_in[3];
    float* out = (float*)d_out;

    const int N = in_sizes[0] / DIM;
    const int E = in_sizes[1] / 2;
    const int* row = ei;
    const int* col = ei + E;

    const size_t ND = (size_t)N * DIM;
    float* ws = (float*)d_ws;
    float* dinv = ws;               // N
    float* p1   = ws + N;           // ND  (A^1 x)
    float* p3   = p1 + ND;          // ND  (A^3 x)
    float* p7   = p3 + ND;          // ND  (A^7 x)
    float* tA   = p7 + ND;          // ND  (ping-pong temp)
    float* weff = tA + ND;          // 4*64*64

    // --- dinv ---
    hipMemsetAsync(dinv, 0, (size_t)N * sizeof(float), stream);
    count_deg_kernel<<<(E + 255) / 256, 256, 0, stream>>>(col, dinv, E);
    dinv_kernel<<<(N + 255) / 256, 256, 0, stream>>>(dinv, N);

    // --- effective W (independent; launch early) ---
    make_weff_kernel<<<16, 256, 0, stream>>>(W, weff);

    const int initGrid = (N * (DIM / 4) + 255) / 256;
    const int scatGrid = (E * 16 + 255) / 256;

    // One propagate: dst = A * src
    auto prop = [&](const float* src, float* dst) {
        selfloop_init_kernel<<<initGrid, 256, 0, stream>>>(src, dinv, dst, N);
        scatter_kernel<<<scatGrid, 256, 0, stream>>>(row, col, dinv, src, dst, E);
    };

    prop(x,  p1);   // A^1
    prop(p1, tA);   // A^2
    prop(tA, p3);   // A^3
    prop(p3, tA);   // A^4
    prop(tA, p7);   // A^5 (p7 used as scratch)
    prop(p7, tA);   // A^6
    prop(tA, p7);   // A^7

    // --- combine ---
    combine_kernel<<<2048, 256, 0, stream>>>(x, p1, p3, p7, weff, b, out, N);
}

// Round 3
// 1027.397 us; speedup vs baseline: 9.0534x; 9.0534x over previous
//
#include <hip/hip_runtime.h>

#define DIM 64

// ---------------------------------------------------------------------------
// deg[col[e]] += 1  (int atomics, one-time CSC build)
// ---------------------------------------------------------------------------
__global__ void count_deg_kernel(const int* __restrict__ col,
                                 int* __restrict__ deg, int E) {
    int e = blockIdx.x * blockDim.x + threadIdx.x;
    if (e < E) atomicAdd(&deg[col[e]], 1);
}

// dinv[i] = rsqrt(deg[i] + 1)   (+1 = self loop; always > 0)
__global__ void dinv_kernel(const int* __restrict__ deg,
                            float* __restrict__ dinv, int N) {
    int i = blockIdx.x * blockDim.x + threadIdx.x;
    if (i < N) dinv[i] = rsqrtf((float)deg[i] + 1.0f);
}

// --------------------------- exclusive scan (3 kernels) --------------------
// K1: per-256-chunk reduce
__global__ void reduce_chunks_kernel(const int* __restrict__ deg,
                                     int* __restrict__ bs, int N) {
    __shared__ int s[256];
    int t = threadIdx.x;
    int i = blockIdx.x * 256 + t;
    s[t] = (i < N) ? deg[i] : 0;
    __syncthreads();
    for (int d = 128; d > 0; d >>= 1) {
        if (t < d) s[t] += s[t + d];
        __syncthreads();
    }
    if (t == 0) bs[blockIdx.x] = s[0];
}

// K2: exclusive scan of block sums (nb <= 1024), single block
__global__ void scan_block_sums_kernel(int* __restrict__ bs, int nb) {
    __shared__ int s[1024];
    int t = threadIdx.x;
    s[t] = (t < nb) ? bs[t] : 0;
    __syncthreads();
    for (int d = 1; d < 1024; d <<= 1) {
        int v = (t >= d) ? s[t - d] : 0;
        __syncthreads();
        s[t] += v;
        __syncthreads();
    }
    if (t < nb) bs[t] = (t == 0) ? 0 : s[t - 1];
}

// K3: per-chunk exclusive scan + block offset -> ptr; also writes ptr[N]
__global__ void scan_chunks_kernel(const int* __restrict__ deg,
                                   const int* __restrict__ bs,
                                   int* __restrict__ ptr, int N) {
    __shared__ int s[256];
    int b = blockIdx.x, t = threadIdx.x;
    int i = b * 256 + t;
    int v = (i < N) ? deg[i] : 0;
    s[t] = v;
    __syncthreads();
    for (int d = 1; d < 256; d <<= 1) {
        int u = (t >= d) ? s[t - d] : 0;
        __syncthreads();
        s[t] += u;
        __syncthreads();
    }
    if (i < N) {
        int p = bs[b] + s[t] - v;
        ptr[i] = p;
        if (i == N - 1) ptr[N] = p + v;
    }
}

// fill CSC buckets: srcs/wts grouped by destination node
__global__ void fill_csc_kernel(const int* __restrict__ row,
                                const int* __restrict__ col,
                                const int* __restrict__ ptr,
                                int* __restrict__ cursor,
                                const float* __restrict__ dinv,
                                int* __restrict__ srcs,
                                float* __restrict__ wts, int E) {
    int e = blockIdx.x * blockDim.x + threadIdx.x;
    if (e < E) {
        int r = row[e], c = col[e];
        int pos = ptr[c] + atomicAdd(&cursor[c], 1);
        srcs[pos] = r;
        wts[pos] = dinv[r] * dinv[c];
    }
}

// ---------------------------------------------------------------------------
// gather-side propagate: one wave per node, lane = feature dim.
//   out[n][lane] = dinv[n]^2 * in[n][lane] + sum_e wts[e] * in[srcs[e]][lane]
// Edge meta loaded cooperatively: 64 edges per vector load, shfl-broadcast.
// ---------------------------------------------------------------------------
__launch_bounds__(256)
__global__ void spmv_gather_kernel(const int* __restrict__ ptr,
                                   const int* __restrict__ srcs,
                                   const float* __restrict__ wts,
                                   const float* __restrict__ dinv,
                                   const float* __restrict__ in,
                                   float* __restrict__ out, int N) {
    int wave = (blockIdx.x * blockDim.x + threadIdx.x) >> 6;
    int lane = threadIdx.x & 63;
    if (wave >= N) return;
    int beg = ptr[wave], end = ptr[wave + 1];
    float d = dinv[wave];
    float acc = d * d * in[(size_t)wave * DIM + lane];
    for (int base = beg; base < end; base += 64) {
        int cnt = end - base;
        if (cnt > 64) cnt = 64;
        int s = 0;
        float w = 0.f;
        if (base + lane < end) {
            s = srcs[base + lane];
            w = wts[base + lane];
        }
        for (int j = 0; j < cnt; ++j) {
            int sj = __shfl(s, j);
            float wj = __shfl(w, j);
            acc += wj * in[(size_t)sj * DIM + lane];
        }
    }
    out[(size_t)wave * DIM + lane] = acc;
}

// ---------------------------------------------------------------------------
// Reference quirk: r never updates, so powers are cumulative:
//   x_agg[1] = A x, x_agg[2] = A^3 x, x_agg[4] = A^7 x.
//   cat@W = x@W3 + p1@(W0-W3+W4) + p3@(W1-W4+W5) + p7@(W2-W5)
// weff layout: [src][k][d], src: 0=x 1=A^1 2=A^3 3=A^7
// ---------------------------------------------------------------------------
__global__ void make_weff_kernel(const float* __restrict__ W,
                                 float* __restrict__ weff) {
    int t = blockIdx.x * blockDim.x + threadIdx.x;
    if (t < 64 * 64) {
        int k = t >> 6, d = t & 63;
        float w0 = W[(0 * 64 + k) * 64 + d];
        float w1 = W[(1 * 64 + k) * 64 + d];
        float w2 = W[(2 * 64 + k) * 64 + d];
        float w3 = W[(3 * 64 + k) * 64 + d];
        float w4 = W[(4 * 64 + k) * 64 + d];
        float w5 = W[(5 * 64 + k) * 64 + d];
        weff[(0 * 64 + k) * 64 + d] = w3;
        weff[(1 * 64 + k) * 64 + d] = w0 - w3 + w4;
        weff[(2 * 64 + k) * 64 + d] = w1 - w4 + w5;
        weff[(3 * 64 + k) * 64 + d] = w2 - w5;
    }
}

// ---------------------------------------------------------------------------
// combine: out[n][d] = relu(b[d] + sum_s sum_k in_s[n][k] * weff[s][k][d])
// ---------------------------------------------------------------------------
__launch_bounds__(256)
__global__ void combine_kernel(const float* __restrict__ x,
                               const float* __restrict__ p1,
                               const float* __restrict__ p3,
                               const float* __restrict__ p7,
                               const float* __restrict__ weff,
                               const float* __restrict__ bias,
                               float* __restrict__ out, int N) {
    __shared__ float sW[4 * 64 * 64];   // [s][k][d]  64 KB
    __shared__ float sIn[16][4 * 64];   // [node][s*64+k] 16 KB

    int tid = threadIdx.x;
    for (int i = tid; i < 4 * 64 * 64; i += 256) sW[i] = weff[i];

    int node = tid >> 4;
    int d4 = (tid & 15) * 4;
    float4 bvec = *(const float4*)(bias + d4);

    int ngroups = (N + 15) / 16;
    for (int g = blockIdx.x; g < ngroups; g += gridDim.x) {
        int n0 = g * 16;
        __syncthreads();
        for (int i = tid; i < 16 * 4 * 16; i += 256) {
            int nd = i >> 6;
            int rem = i & 63;
            int src = rem >> 4;
            int f = rem & 15;
            int n = n0 + nd;
            float4 v = make_float4(0.f, 0.f, 0.f, 0.f);
            if (n < N) {
                const float* p = (src == 0) ? x : (src == 1) ? p1
                               : (src == 2) ? p3 : p7;
                v = *(const float4*)(p + (size_t)n * DIM + f * 4);
            }
            ((float4*)sIn[nd])[src * 16 + f] = v;
        }
        __syncthreads();

        float4 acc = bvec;
        #pragma unroll
        for (int s = 0; s < 4; ++s) {
            const float* ip = &sIn[node][s * 64];
            const float* wp = &sW[s * 4096 + d4];
            #pragma unroll 16
            for (int k = 0; k < 64; ++k) {
                float a = ip[k];
                float4 w = *(const float4*)(wp + k * 64);
                acc.x += a * w.x;
                acc.y += a * w.y;
                acc.z += a * w.z;
                acc.w += a * w.w;
            }
        }
        int n = n0 + node;
        if (n < N) {
            float4 r;
            r.x = fmaxf(acc.x, 0.f);
            r.y = fmaxf(acc.y, 0.f);
            r.z = fmaxf(acc.z, 0.f);
            r.w = fmaxf(acc.w, 0.f);
            *(float4*)(out + (size_t)n * DIM + d4) = r;
        }
    }
}

extern "C" void kernel_launch(void* const* d_in, const int* in_sizes, int n_in,
                              void* d_out, int out_size, void* d_ws, size_t ws_size,
                              hipStream_t stream) {
    const float* x  = (const float*)d_in[0];
    const int*   ei = (const int*)d_in[1];
    const float* W  = (const float*)d_in[2];
    const float* b  = (const float*)d_in[3];
    float* out = (float*)d_out;

    const int N = in_sizes[0] / DIM;
    const int E = in_sizes[1] / 2;
    const int* row = ei;
    const int* col = ei + E;

    const size_t ND = (size_t)N * DIM;
    float* ws = (float*)d_ws;
    float* dinv = ws;               // N
    float* p1   = ws + N;           // ND  (A^1 x)
    float* p3   = p1 + ND;          // ND  (A^3 x)
    float* p7   = p3 + ND;          // ND  (A^7 x)
    float* tA   = p7 + ND;          // ND  (ping-pong temp)
    float* weff = tA + ND;          // 4*64*64
    float* wts  = weff + 4 * 64 * 64;           // E floats
    int*   deg  = (int*)(wts + E);              // N
    int*   ptr  = deg + N;                      // N+1
    int*   cur  = ptr + N + 1;                  // N
    int*   bs   = cur + N;                      // nblocks (<=1024)
    int*   srcs = bs + 1024;                    // E

    const int nb = (N + 255) / 256;             // scan chunks (391 for N=100k)

    // --- degree + dinv ---
    hipMemsetAsync(deg, 0, (size_t)N * sizeof(int), stream);
    hipMemsetAsync(cur, 0, (size_t)N * sizeof(int), stream);
    count_deg_kernel<<<(E + 255) / 256, 256, 0, stream>>>(col, deg, E);
    dinv_kernel<<<nb, 256, 0, stream>>>(deg, dinv, N);

    // --- exclusive scan deg -> ptr ---
    reduce_chunks_kernel<<<nb, 256, 0, stream>>>(deg, bs, N);
    scan_block_sums_kernel<<<1, 1024, 0, stream>>>(bs, nb);
    scan_chunks_kernel<<<nb, 256, 0, stream>>>(deg, bs, ptr, N);

    // --- CSC fill ---
    fill_csc_kernel<<<(E + 255) / 256, 256, 0, stream>>>(row, col, ptr, cur,
                                                         dinv, srcs, wts, E);

    // --- effective W ---
    make_weff_kernel<<<16, 256, 0, stream>>>(W, weff);

    const int propGrid = (int)(((size_t)N * 64 + 255) / 256);
    auto prop = [&](const float* src, float* dst) {
        spmv_gather_kernel<<<propGrid, 256, 0, stream>>>(ptr, srcs, wts, dinv,
                                                         src, dst, N);
    };

    prop(x,  p1);   // A^1
    prop(p1, tA);   // A^2
    prop(tA, p3);   // A^3
    prop(p3, tA);   // A^4
    prop(tA, p7);   // A^5 (p7 as scratch)
    prop(p7, tA);   // A^6
    prop(tA, p7);   // A^7

    // --- combine ---
    combine_kernel<<<2048, 256, 0, stream>>>(x, p1, p3, p7, weff, b, out, N);
}

// Round 4
// 790.864 us; speedup vs baseline: 11.7611x; 1.2991x over previous
//
#include <hip/hip_runtime.h>

#define DIM 64

// ---------------------------------------------------------------------------
// deg[col[e]] += 1  (int atomics, one-time CSC build)
// ---------------------------------------------------------------------------
__global__ void count_deg_kernel(const int* __restrict__ col,
                                 int* __restrict__ deg, int E) {
    int e = blockIdx.x * blockDim.x + threadIdx.x;
    if (e < E) atomicAdd(&deg[col[e]], 1);
}

// dinv[i] = rsqrt(deg+1), rdinv[i] = sqrt(deg+1)
__global__ void dinv_kernel(const int* __restrict__ deg,
                            float* __restrict__ dinv,
                            float* __restrict__ rdinv, int N) {
    int i = blockIdx.x * blockDim.x + threadIdx.x;
    if (i < N) {
        float d = (float)deg[i] + 1.0f;
        dinv[i] = rsqrtf(d);
        rdinv[i] = sqrtf(d);
    }
}

// --------------------------- exclusive scan (3 kernels) --------------------
__global__ void reduce_chunks_kernel(const int* __restrict__ deg,
                                     int* __restrict__ bs, int N) {
    __shared__ int s[256];
    int t = threadIdx.x;
    int i = blockIdx.x * 256 + t;
    s[t] = (i < N) ? deg[i] : 0;
    __syncthreads();
    for (int d = 128; d > 0; d >>= 1) {
        if (t < d) s[t] += s[t + d];
        __syncthreads();
    }
    if (t == 0) bs[blockIdx.x] = s[0];
}

__global__ void scan_block_sums_kernel(int* __restrict__ bs, int nb) {
    __shared__ int s[1024];
    int t = threadIdx.x;
    s[t] = (t < nb) ? bs[t] : 0;
    __syncthreads();
    for (int d = 1; d < 1024; d <<= 1) {
        int v = (t >= d) ? s[t - d] : 0;
        __syncthreads();
        s[t] += v;
        __syncthreads();
    }
    if (t < nb) bs[t] = (t == 0) ? 0 : s[t - 1];
}

__global__ void scan_chunks_kernel(const int* __restrict__ deg,
                                   const int* __restrict__ bs,
                                   int* __restrict__ ptr, int N) {
    __shared__ int s[256];
    int b = blockIdx.x, t = threadIdx.x;
    int i = b * 256 + t;
    int v = (i < N) ? deg[i] : 0;
    s[t] = v;
    __syncthreads();
    for (int d = 1; d < 256; d <<= 1) {
        int u = (t >= d) ? s[t - d] : 0;
        __syncthreads();
        s[t] += u;
        __syncthreads();
    }
    if (i < N) {
        int p = bs[b] + s[t] - v;
        ptr[i] = p;
        if (i == N - 1) ptr[N] = p + v;
    }
}

// fill CSC buckets: srcs grouped by destination node (no weights needed!)
__global__ void fill_csc_kernel(const int* __restrict__ row,
                                const int* __restrict__ col,
                                const int* __restrict__ ptr,
                                int* __restrict__ cursor,
                                int* __restrict__ srcs, int E) {
    int e = blockIdx.x * blockDim.x + threadIdx.x;
    if (e < E) {
        int c = col[e];
        int pos = ptr[c] + atomicAdd(&cursor[c], 1);
        srcs[pos] = row[e];
    }
}

// v0 = dinv * x
__global__ void scale_init_kernel(const float* __restrict__ x,
                                  const float* __restrict__ dinv,
                                  float* __restrict__ v, int N) {
    int t = blockIdx.x * blockDim.x + threadIdx.x;
    if (t < N * (DIM / 4)) {
        int n = t >> 4;
        float d = dinv[n];
        float4 a = ((const float4*)x)[t];
        a.x *= d; a.y *= d; a.z *= d; a.w *= d;
        ((float4*)v)[t] = a;
    }
}

// ---------------------------------------------------------------------------
// v-space propagate (all edge weights == 1):
//   vout[n][lane] = dinv[n]^2 * ( v[n][lane] + sum_{e->n} v[srcs[e]][lane] )
// One wave per node, lane = dim. Inner loop unrolled x8 with 8 independent
// accumulators so 8 gathers are in flight per wave (MLP).
// ---------------------------------------------------------------------------
__launch_bounds__(256)
__global__ void spmv_v_kernel(const int* __restrict__ ptr,
                              const int* __restrict__ srcs,
                              const float* __restrict__ dinv,
                              const float* __restrict__ v,
                              float* __restrict__ vout, int N) {
    int wave = (blockIdx.x * blockDim.x + threadIdx.x) >> 6;
    int lane = threadIdx.x & 63;
    if (wave >= N) return;
    int beg = ptr[wave], end = ptr[wave + 1];
    float a0 = v[(size_t)wave * DIM + lane];   // self-loop term
    float a1 = 0.f, a2 = 0.f, a3 = 0.f;
    float a4 = 0.f, a5 = 0.f, a6 = 0.f, a7 = 0.f;
    for (int base = beg; base < end; base += 64) {
        int s = (base + lane < end) ? srcs[base + lane] : 0;
        int cnt = end - base;
        if (cnt > 64) cnt = 64;
        int j = 0;
        for (; j + 8 <= cnt; j += 8) {
            int s0 = __shfl(s, j + 0);
            int s1 = __shfl(s, j + 1);
            int s2 = __shfl(s, j + 2);
            int s3 = __shfl(s, j + 3);
            int s4 = __shfl(s, j + 4);
            int s5 = __shfl(s, j + 5);
            int s6 = __shfl(s, j + 6);
            int s7 = __shfl(s, j + 7);
            float x0 = v[(size_t)s0 * DIM + lane];
            float x1 = v[(size_t)s1 * DIM + lane];
            float x2 = v[(size_t)s2 * DIM + lane];
            float x3 = v[(size_t)s3 * DIM + lane];
            float x4 = v[(size_t)s4 * DIM + lane];
            float x5 = v[(size_t)s5 * DIM + lane];
            float x6 = v[(size_t)s6 * DIM + lane];
            float x7 = v[(size_t)s7 * DIM + lane];
            a0 += x0; a1 += x1; a2 += x2; a3 += x3;
            a4 += x4; a5 += x5; a6 += x6; a7 += x7;
        }
        for (; j < cnt; ++j) {
            int sj = __shfl(s, j);
            a0 += v[(size_t)sj * DIM + lane];
        }
    }
    float d = dinv[wave];
    float sum = ((a0 + a1) + (a2 + a3)) + ((a4 + a5) + (a6 + a7));
    vout[(size_t)wave * DIM + lane] = d * d * sum;
}

// ---------------------------------------------------------------------------
// Reference quirk: r never updates, so powers are cumulative:
//   x_agg[1] = A x, x_agg[2] = A^3 x, x_agg[4] = A^7 x.
//   cat@W = x@W3 + p1@(W0-W3+W4) + p3@(W1-W4+W5) + p7@(W2-W5)
// weff layout: [src][k][d], src: 0=x 1=A^1 2=A^3 3=A^7
// ---------------------------------------------------------------------------
__global__ void make_weff_kernel(const float* __restrict__ W,
                                 float* __restrict__ weff) {
    int t = blockIdx.x * blockDim.x + threadIdx.x;
    if (t < 64 * 64) {
        int k = t >> 6, d = t & 63;
        float w0 = W[(0 * 64 + k) * 64 + d];
        float w1 = W[(1 * 64 + k) * 64 + d];
        float w2 = W[(2 * 64 + k) * 64 + d];
        float w3 = W[(3 * 64 + k) * 64 + d];
        float w4 = W[(4 * 64 + k) * 64 + d];
        float w5 = W[(5 * 64 + k) * 64 + d];
        weff[(0 * 64 + k) * 64 + d] = w3;
        weff[(1 * 64 + k) * 64 + d] = w0 - w3 + w4;
        weff[(2 * 64 + k) * 64 + d] = w1 - w4 + w5;
        weff[(3 * 64 + k) * 64 + d] = w2 - w5;
    }
}

// ---------------------------------------------------------------------------
// combine: out[n][d] = relu(b[d] + sum_s sum_k f_s[n][k] * weff[s][k][d])
// f_0 = x; f_s (s>=1) = rdinv[n] * v_s[n]  (un-scale from v-space)
// ---------------------------------------------------------------------------
__launch_bounds__(256)
__global__ void combine_kernel(const float* __restrict__ x,
                               const float* __restrict__ v1,
                               const float* __restrict__ v3,
                               const float* __restrict__ v7,
                               const float* __restrict__ rdinv,
                               const float* __restrict__ weff,
                               const float* __restrict__ bias,
                               float* __restrict__ out, int N) {
    __shared__ float sW[4 * 64 * 64];   // [s][k][d]  64 KB
    __shared__ float sIn[16][4 * 64];   // [node][s*64+k] 16 KB

    int tid = threadIdx.x;
    for (int i = tid; i < 4 * 64 * 64; i += 256) sW[i] = weff[i];

    int node = tid >> 4;
    int d4 = (tid & 15) * 4;
    float4 bvec = *(const float4*)(bias + d4);

    int ngroups = (N + 15) / 16;
    for (int g = blockIdx.x; g < ngroups; g += gridDim.x) {
        int n0 = g * 16;
        __syncthreads();
        for (int i = tid; i < 16 * 4 * 16; i += 256) {
            int nd = i >> 6;
            int rem = i & 63;
            int src = rem >> 4;
            int f = rem & 15;
            int n = n0 + nd;
            float4 v = make_float4(0.f, 0.f, 0.f, 0.f);
            if (n < N) {
                const float* p = (src == 0) ? x : (src == 1) ? v1
                               : (src == 2) ? v3 : v7;
                v = *(const float4*)(p + (size_t)n * DIM + f * 4);
                if (src != 0) {
                    float rd = rdinv[n];
                    v.x *= rd; v.y *= rd; v.z *= rd; v.w *= rd;
                }
            }
            ((float4*)sIn[nd])[src * 16 + f] = v;
        }
        __syncthreads();

        float4 acc = bvec;
        #pragma unroll
        for (int s = 0; s < 4; ++s) {
            const float* ip = &sIn[node][s * 64];
            const float* wp = &sW[s * 4096 + d4];
            #pragma unroll 16
            for (int k = 0; k < 64; ++k) {
                float a = ip[k];
                float4 w = *(const float4*)(wp + k * 64);
                acc.x += a * w.x;
                acc.y += a * w.y;
                acc.z += a * w.z;
                acc.w += a * w.w;
            }
        }
        int n = n0 + node;
        if (n < N) {
            float4 r;
            r.x = fmaxf(acc.x, 0.f);
            r.y = fmaxf(acc.y, 0.f);
            r.z = fmaxf(acc.z, 0.f);
            r.w = fmaxf(acc.w, 0.f);
            *(float4*)(out + (size_t)n * DIM + d4) = r;
        }
    }
}

extern "C" void kernel_launch(void* const* d_in, const int* in_sizes, int n_in,
                              void* d_out, int out_size, void* d_ws, size_t ws_size,
                              hipStream_t stream) {
    const float* x  = (const float*)d_in[0];
    const int*   ei = (const int*)d_in[1];
    const float* W  = (const float*)d_in[2];
    const float* b  = (const float*)d_in[3];
    float* out = (float*)d_out;

    const int N = in_sizes[0] / DIM;
    const int E = in_sizes[1] / 2;
    const int* row = ei;
    const int* col = ei + E;

    const size_t ND = (size_t)N * DIM;
    float* ws = (float*)d_ws;
    float* dinv  = ws;                  // N
    float* rdinv = dinv + N;            // N
    float* v1    = rdinv + N;           // ND  (v-space A^1)
    float* v3    = v1 + ND;             // ND  (v-space A^3)
    float* v7    = v3 + ND;             // ND  (v-space A^7)
    float* tA    = v7 + ND;             // ND  (ping-pong temp)
    float* weff  = tA + ND;             // 4*64*64
    int*   deg   = (int*)(weff + 4 * 64 * 64);  // N
    int*   ptr   = deg + N;             // N+1
    int*   cur   = ptr + N + 1;         // N
    int*   bs    = cur + N;             // <=1024
    int*   srcs  = bs + 1024;           // E

    const int nb = (N + 255) / 256;

    // --- degree + dinv/rdinv ---
    hipMemsetAsync(deg, 0, (size_t)N * sizeof(int), stream);
    hipMemsetAsync(cur, 0, (size_t)N * sizeof(int), stream);
    count_deg_kernel<<<(E + 255) / 256, 256, 0, stream>>>(col, deg, E);
    dinv_kernel<<<nb, 256, 0, stream>>>(deg, dinv, rdinv, N);

    // --- exclusive scan deg -> ptr ---
    reduce_chunks_kernel<<<nb, 256, 0, stream>>>(deg, bs, N);
    scan_block_sums_kernel<<<1, 1024, 0, stream>>>(bs, nb);
    scan_chunks_kernel<<<nb, 256, 0, stream>>>(deg, bs, ptr, N);

    // --- CSC fill (srcs only, no weights) ---
    fill_csc_kernel<<<(E + 255) / 256, 256, 0, stream>>>(row, col, ptr, cur,
                                                         srcs, E);

    // --- effective W ---
    make_weff_kernel<<<16, 256, 0, stream>>>(W, weff);

    const int initGrid = (N * (DIM / 4) + 255) / 256;
    const int propGrid = (int)(((size_t)N * 64 + 255) / 256);
    auto prop = [&](const float* src, float* dst) {
        spmv_v_kernel<<<propGrid, 256, 0, stream>>>(ptr, srcs, dinv, src, dst, N);
    };

    // v0 = dinv * x  (in tA)
    scale_init_kernel<<<initGrid, 256, 0, stream>>>(x, dinv, tA, N);
    prop(tA, v1);   // v1
    prop(v1, tA);   // v2
    prop(tA, v3);   // v3
    prop(v3, tA);   // v4
    prop(tA, v7);   // v5 (v7 as scratch)
    prop(v7, tA);   // v6
    prop(tA, v7);   // v7

    // --- combine ---
    combine_kernel<<<2048, 256, 0, stream>>>(x, v1, v3, v7, rdinv, weff, b,
                                             out, N);
}

// Round 5
// 712.608 us; speedup vs baseline: 13.0526x; 1.1098x over previous
//
#include <hip/hip_runtime.h>

#define DIM 64

typedef __attribute__((ext_vector_type(8))) short short8;
typedef __attribute__((ext_vector_type(4))) float floatx4;

__device__ __forceinline__ unsigned short f2bf(float f) {
    unsigned u = __float_as_uint(f);
    u += 0x7FFFu + ((u >> 16) & 1u);     // round-to-nearest-even
    return (unsigned short)(u >> 16);
}

// ---------------------------------------------------------------------------
// deg[col[e]] += 1  (int atomics, one-time CSC build)
// ---------------------------------------------------------------------------
__global__ void count_deg_kernel(const int* __restrict__ col,
                                 int* __restrict__ deg, int E) {
    int e = blockIdx.x * blockDim.x + threadIdx.x;
    if (e < E) atomicAdd(&deg[col[e]], 1);
}

// dinv[i] = rsqrt(deg+1), rdinv[i] = sqrt(deg+1)
__global__ void dinv_kernel(const int* __restrict__ deg,
                            float* __restrict__ dinv,
                            float* __restrict__ rdinv, int N) {
    int i = blockIdx.x * blockDim.x + threadIdx.x;
    if (i < N) {
        float d = (float)deg[i] + 1.0f;
        dinv[i] = rsqrtf(d);
        rdinv[i] = sqrtf(d);
    }
}

// --------------------------- exclusive scan (3 kernels) --------------------
__global__ void reduce_chunks_kernel(const int* __restrict__ deg,
                                     int* __restrict__ bs, int N) {
    __shared__ int s[256];
    int t = threadIdx.x;
    int i = blockIdx.x * 256 + t;
    s[t] = (i < N) ? deg[i] : 0;
    __syncthreads();
    for (int d = 128; d > 0; d >>= 1) {
        if (t < d) s[t] += s[t + d];
        __syncthreads();
    }
    if (t == 0) bs[blockIdx.x] = s[0];
}

__global__ void scan_block_sums_kernel(int* __restrict__ bs, int nb) {
    __shared__ int s[1024];
    int t = threadIdx.x;
    s[t] = (t < nb) ? bs[t] : 0;
    __syncthreads();
    for (int d = 1; d < 1024; d <<= 1) {
        int v = (t >= d) ? s[t - d] : 0;
        __syncthreads();
        s[t] += v;
        __syncthreads();
    }
    if (t < nb) bs[t] = (t == 0) ? 0 : s[t - 1];
}

__global__ void scan_chunks_kernel(const int* __restrict__ deg,
                                   const int* __restrict__ bs,
                                   int* __restrict__ ptr, int N) {
    __shared__ int s[256];
    int b = blockIdx.x, t = threadIdx.x;
    int i = b * 256 + t;
    int v = (i < N) ? deg[i] : 0;
    s[t] = v;
    __syncthreads();
    for (int d = 1; d < 256; d <<= 1) {
        int u = (t >= d) ? s[t - d] : 0;
        __syncthreads();
        s[t] += u;
        __syncthreads();
    }
    if (i < N) {
        int p = bs[b] + s[t] - v;
        ptr[i] = p;
        if (i == N - 1) ptr[N] = p + v;
    }
}

// fill CSC buckets: srcs grouped by destination node
__global__ void fill_csc_kernel(const int* __restrict__ row,
                                const int* __restrict__ col,
                                const int* __restrict__ ptr,
                                int* __restrict__ cursor,
                                int* __restrict__ srcs, int E) {
    int e = blockIdx.x * blockDim.x + threadIdx.x;
    if (e < E) {
        int c = col[e];
        int pos = ptr[c] + atomicAdd(&cursor[c], 1);
        srcs[pos] = row[e];
    }
}

// v0 = dinv * x
__global__ void scale_init_kernel(const float* __restrict__ x,
                                  const float* __restrict__ dinv,
                                  float* __restrict__ v, int N) {
    int t = blockIdx.x * blockDim.x + threadIdx.x;
    if (t < N * (DIM / 4)) {
        int n = t >> 4;
        float d = dinv[n];
        float4 a = ((const float4*)x)[t];
        a.x *= d; a.y *= d; a.z *= d; a.w *= d;
        ((float4*)v)[t] = a;
    }
}

// ---------------------------------------------------------------------------
// v-space propagate (all edge weights == 1):
//   vout[n][lane] = dinv[n]^2 * ( v[n][lane] + sum_{e->n} v[srcs[e]][lane] )
// One wave per node, lane = dim. beg/end forced to SGPR via readfirstlane so
// srcs[j] loads scalarize (s_load); gather index is 32-bit SGPR*64+lane ->
// ~2 VALU + 1 load per edge, 8 independent accumulators for MLP.
// ---------------------------------------------------------------------------
__launch_bounds__(256)
__global__ void spmv_v_kernel(const int* __restrict__ ptr,
                              const int* __restrict__ srcs,
                              const float* __restrict__ dinv,
                              const float* __restrict__ v,
                              float* __restrict__ vout, int N) {
    int wave = blockIdx.x * 4 + (threadIdx.x >> 6);
    int lane = threadIdx.x & 63;
    if (wave >= N) return;
    int beg = __builtin_amdgcn_readfirstlane(ptr[wave]);
    int end = __builtin_amdgcn_readfirstlane(ptr[wave + 1]);
    unsigned base = (unsigned)wave * DIM + (unsigned)lane;
    float a0 = v[base];   // self-loop term
    float a1 = 0.f, a2 = 0.f, a3 = 0.f;
    float a4 = 0.f, a5 = 0.f, a6 = 0.f, a7 = 0.f;
    int j = beg;
    for (; j + 8 <= end; j += 8) {
        int s0 = srcs[j + 0], s1 = srcs[j + 1];
        int s2 = srcs[j + 2], s3 = srcs[j + 3];
        int s4 = srcs[j + 4], s5 = srcs[j + 5];
        int s6 = srcs[j + 6], s7 = srcs[j + 7];
        a0 += v[(unsigned)s0 * DIM + (unsigned)lane];
        a1 += v[(unsigned)s1 * DIM + (unsigned)lane];
        a2 += v[(unsigned)s2 * DIM + (unsigned)lane];
        a3 += v[(unsigned)s3 * DIM + (unsigned)lane];
        a4 += v[(unsigned)s4 * DIM + (unsigned)lane];
        a5 += v[(unsigned)s5 * DIM + (unsigned)lane];
        a6 += v[(unsigned)s6 * DIM + (unsigned)lane];
        a7 += v[(unsigned)s7 * DIM + (unsigned)lane];
    }
    if (j + 4 <= end) {
        int s0 = srcs[j + 0], s1 = srcs[j + 1];
        int s2 = srcs[j + 2], s3 = srcs[j + 3];
        a1 += v[(unsigned)s0 * DIM + (unsigned)lane];
        a2 += v[(unsigned)s1 * DIM + (unsigned)lane];
        a3 += v[(unsigned)s2 * DIM + (unsigned)lane];
        a4 += v[(unsigned)s3 * DIM + (unsigned)lane];
        j += 4;
    }
    for (; j < end; ++j)
        a0 += v[(unsigned)srcs[j] * DIM + (unsigned)lane];
    float d = dinv[wave];
    float sum = ((a0 + a1) + (a2 + a3)) + ((a4 + a5) + (a6 + a7));
    vout[base] = d * d * sum;
}

// ---------------------------------------------------------------------------
// Reference quirk: r never updates -> powers cumulative:
//   x_agg[1] = A x, x_agg[2] = A^3 x, x_agg[4] = A^7 x.
//   cat@W = x@W3 + p1@(W0-W3+W4) + p3@(W1-W4+W5) + p7@(W2-W5)
// weff layout: [src][k][d] flattened = [kk][d] with kk = src*64+k
// ---------------------------------------------------------------------------
__global__ void make_weff_kernel(const float* __restrict__ W,
                                 float* __restrict__ weff) {
    int t = blockIdx.x * blockDim.x + threadIdx.x;
    if (t < 64 * 64) {
        int k = t >> 6, d = t & 63;
        float w0 = W[(0 * 64 + k) * 64 + d];
        float w1 = W[(1 * 64 + k) * 64 + d];
        float w2 = W[(2 * 64 + k) * 64 + d];
        float w3 = W[(3 * 64 + k) * 64 + d];
        float w4 = W[(4 * 64 + k) * 64 + d];
        float w5 = W[(5 * 64 + k) * 64 + d];
        weff[(0 * 64 + k) * 64 + d] = w3;
        weff[(1 * 64 + k) * 64 + d] = w0 - w3 + w4;
        weff[(2 * 64 + k) * 64 + d] = w1 - w4 + w5;
        weff[(3 * 64 + k) * 64 + d] = w2 - w5;
    }
}

// ---------------------------------------------------------------------------
// MFMA combine: out[16-node tile][64 dims] via mfma_f32_16x16x32_bf16.
// Wave w owns dim slice [16w,16w+16). K=256 (4 src x 64) in 8 mfma steps.
// Verified gfx950 layouts (m89/m91): A: m=lane&15, k=quad*8+j;
//                                    B: n=lane&15, k=quad*8+j;
//                                    D: col=lane&15, row=quad*4+reg.
// LDS rows padded to 264 shorts: stride 132 dwords -> bank +4 per row ->
// worst 2-way aliasing (free).
// ---------------------------------------------------------------------------
__launch_bounds__(256)
__global__ void combine_mfma_kernel(const float* __restrict__ x,
                                    const float* __restrict__ v1,
                                    const float* __restrict__ v3,
                                    const float* __restrict__ v7,
                                    const float* __restrict__ rdinv,
                                    const float* __restrict__ weff,
                                    const float* __restrict__ bias,
                                    float* __restrict__ out, int N) {
    __shared__ unsigned short sWt[64][264];  // [dim][kk] transposed bf16 W
    __shared__ unsigned short sA[16][264];   // [node][kk] bf16 inputs

    int tid = threadIdx.x;
    // stage transposed bf16 weights once per block
    for (int i = tid; i < 64 * 256; i += 256) {
        int kk = i >> 6, d = i & 63;
        sWt[d][kk] = f2bf(weff[i]);
    }
    int lane = tid & 63;
    int w = tid >> 6;            // wave id -> dim slice
    int quad = lane >> 4;
    int col = lane & 15;
    int dim = w * 16 + col;
    float bv = bias[dim];

    int ngroups = (N + 15) / 16;
    for (int g = blockIdx.x; g < ngroups; g += gridDim.x) {
        int n0 = g * 16;
        __syncthreads();
        // stage 16 nodes x 4 src x 64 dims -> bf16 (rdinv un-scale for v*)
        for (int i = tid; i < 1024; i += 256) {
            int node = i >> 6;
            int rem = i & 63;
            int src = rem >> 4;
            int f = rem & 15;
            int n = n0 + node;
            float4 val = make_float4(0.f, 0.f, 0.f, 0.f);
            if (n < N) {
                const float* p = (src == 0) ? x : (src == 1) ? v1
                               : (src == 2) ? v3 : v7;
                val = *(const float4*)(p + (size_t)n * DIM + f * 4);
                if (src) {
                    float rd = rdinv[n];
                    val.x *= rd; val.y *= rd; val.z *= rd; val.w *= rd;
                }
            }
            ushort4 bq;
            bq.x = f2bf(val.x); bq.y = f2bf(val.y);
            bq.z = f2bf(val.z); bq.w = f2bf(val.w);
            *(ushort4*)&sA[node][src * 64 + f * 4] = bq;
        }
        __syncthreads();

        floatx4 acc = {0.f, 0.f, 0.f, 0.f};
        #pragma unroll
        for (int t = 0; t < 8; ++t) {
            int k0 = t * 32 + quad * 8;
            short8 af = *(const short8*)&sA[col][k0];
            short8 bf = *(const short8*)&sWt[dim][k0];
            acc = __builtin_amdgcn_mfma_f32_16x16x32_bf16(af, bf, acc, 0, 0, 0);
        }
        #pragma unroll
        for (int r = 0; r < 4; ++r) {
            int n = n0 + quad * 4 + r;
            if (n < N) {
                float vv = acc[r] + bv;
                out[(size_t)n * DIM + dim] = fmaxf(vv, 0.f);
            }
        }
    }
}

extern "C" void kernel_launch(void* const* d_in, const int* in_sizes, int n_in,
                              void* d_out, int out_size, void* d_ws, size_t ws_size,
                              hipStream_t stream) {
    const float* x  = (const float*)d_in[0];
    const int*   ei = (const int*)d_in[1];
    const float* W  = (const float*)d_in[2];
    const float* b  = (const float*)d_in[3];
    float* out = (float*)d_out;

    const int N = in_sizes[0] / DIM;
    const int E = in_sizes[1] / 2;
    const int* row = ei;
    const int* col = ei + E;

    const size_t ND = (size_t)N * DIM;
    float* ws = (float*)d_ws;
    float* dinv  = ws;                  // N
    float* rdinv = dinv + N;            // N
    float* v1    = rdinv + N;           // ND
    float* v3    = v1 + ND;             // ND
    float* v7    = v3 + ND;             // ND
    float* tA    = v7 + ND;             // ND
    float* weff  = tA + ND;             // 4*64*64
    int*   deg   = (int*)(weff + 4 * 64 * 64);  // N
    int*   ptr   = deg + N;             // N+1
    int*   cur   = ptr + N + 1;         // N
    int*   bs    = cur + N;             // <=1024
    int*   srcs  = bs + 1024;           // E

    const int nb = (N + 255) / 256;

    // --- degree + dinv/rdinv ---
    hipMemsetAsync(deg, 0, (size_t)N * sizeof(int), stream);
    hipMemsetAsync(cur, 0, (size_t)N * sizeof(int), stream);
    count_deg_kernel<<<(E + 255) / 256, 256, 0, stream>>>(col, deg, E);
    dinv_kernel<<<nb, 256, 0, stream>>>(deg, dinv, rdinv, N);

    // --- exclusive scan deg -> ptr ---
    reduce_chunks_kernel<<<nb, 256, 0, stream>>>(deg, bs, N);
    scan_block_sums_kernel<<<1, 1024, 0, stream>>>(bs, nb);
    scan_chunks_kernel<<<nb, 256, 0, stream>>>(deg, bs, ptr, N);

    // --- CSC fill ---
    fill_csc_kernel<<<(E + 255) / 256, 256, 0, stream>>>(row, col, ptr, cur,
                                                         srcs, E);

    // --- effective W ---
    make_weff_kernel<<<16, 256, 0, stream>>>(W, weff);

    const int initGrid = (N * (DIM / 4) + 255) / 256;
    const int propGrid = (N + 3) / 4;   // 4 nodes (waves) per 256-thread block
    auto prop = [&](const float* src, float* dst) {
        spmv_v_kernel<<<propGrid, 256, 0, stream>>>(ptr, srcs, dinv, src, dst, N);
    };

    // v0 = dinv * x  (in tA)
    scale_init_kernel<<<initGrid, 256, 0, stream>>>(x, dinv, tA, N);
    prop(tA, v1);   // v1
    prop(v1, tA);   // v2
    prop(tA, v3);   // v3
    prop(v3, tA);   // v4
    prop(tA, v7);   // v5 (v7 as scratch)
    prop(v7, tA);   // v6
    prop(tA, v7);   // v7

    // --- combine (MFMA) ---
    combine_mfma_kernel<<<1024, 256, 0, stream>>>(x, v1, v3, v7, rdinv, weff,
                                                  b, out, N);
}

// Round 7
// 616.336 us; speedup vs baseline: 15.0914x; 1.1562x over previous
//
#include <hip/hip_runtime.h>

#define DIM 64

typedef __attribute__((ext_vector_type(8))) _Float16 half8;
typedef __attribute__((ext_vector_type(4))) _Float16 half4;
typedef __attribute__((ext_vector_type(4))) float floatx4;

// ---------------------------------------------------------------------------
// deg[col[e]] += 1  (int atomics, one-time CSC build)
// ---------------------------------------------------------------------------
__global__ void count_deg_kernel(const int* __restrict__ col,
                                 int* __restrict__ deg, int E) {
    int e = blockIdx.x * blockDim.x + threadIdx.x;
    if (e < E) atomicAdd(&deg[col[e]], 1);
}

// dinv[i] = rsqrt(deg+1), rdinv[i] = sqrt(deg+1)
__global__ void dinv_kernel(const int* __restrict__ deg,
                            float* __restrict__ dinv,
                            float* __restrict__ rdinv, int N) {
    int i = blockIdx.x * blockDim.x + threadIdx.x;
    if (i < N) {
        float d = (float)deg[i] + 1.0f;
        dinv[i] = rsqrtf(d);
        rdinv[i] = sqrtf(d);
    }
}

// --------------------------- exclusive scan (3 kernels) --------------------
__global__ void reduce_chunks_kernel(const int* __restrict__ deg,
                                     int* __restrict__ bs, int N) {
    __shared__ int s[256];
    int t = threadIdx.x;
    int i = blockIdx.x * 256 + t;
    s[t] = (i < N) ? deg[i] : 0;
    __syncthreads();
    for (int d = 128; d > 0; d >>= 1) {
        if (t < d) s[t] += s[t + d];
        __syncthreads();
    }
    if (t == 0) bs[blockIdx.x] = s[0];
}

__global__ void scan_block_sums_kernel(int* __restrict__ bs, int nb) {
    __shared__ int s[1024];
    int t = threadIdx.x;
    s[t] = (t < nb) ? bs[t] : 0;
    __syncthreads();
    for (int d = 1; d < 1024; d <<= 1) {
        int v = (t >= d) ? s[t - d] : 0;
        __syncthreads();
        s[t] += v;
        __syncthreads();
    }
    if (t < nb) bs[t] = (t == 0) ? 0 : s[t - 1];
}

__global__ void scan_chunks_kernel(const int* __restrict__ deg,
                                   const int* __restrict__ bs,
                                   int* __restrict__ ptr, int N) {
    __shared__ int s[256];
    int b = blockIdx.x, t = threadIdx.x;
    int i = b * 256 + t;
    int v = (i < N) ? deg[i] : 0;
    s[t] = v;
    __syncthreads();
    for (int d = 1; d < 256; d <<= 1) {
        int u = (t >= d) ? s[t - d] : 0;
        __syncthreads();
        s[t] += u;
        __syncthreads();
    }
    if (i < N) {
        int p = bs[b] + s[t] - v;
        ptr[i] = p;
        if (i == N - 1) ptr[N] = p + v;
    }
}

// fill CSC buckets: srcs grouped by destination node
__global__ void fill_csc_kernel(const int* __restrict__ row,
                                const int* __restrict__ col,
                                const int* __restrict__ ptr,
                                int* __restrict__ cursor,
                                int* __restrict__ srcs, int E) {
    int e = blockIdx.x * blockDim.x + threadIdx.x;
    if (e < E) {
        int c = col[e];
        int pos = ptr[c] + atomicAdd(&cursor[c], 1);
        srcs[pos] = row[e];
    }
}

// v0 = dinv * x  (fp32 -> fp16 v-space), one thread per 4 dims
__global__ void scale_init_kernel(const float* __restrict__ x,
                                  const float* __restrict__ dinv,
                                  _Float16* __restrict__ v, int N) {
    int t = blockIdx.x * blockDim.x + threadIdx.x;
    if (t < N * (DIM / 4)) {
        int n = t >> 4;
        float d = dinv[n];
        float4 a = ((const float4*)x)[t];
        half4 h;
        h.x = (_Float16)(a.x * d);
        h.y = (_Float16)(a.y * d);
        h.z = (_Float16)(a.z * d);
        h.w = (_Float16)(a.w * d);
        ((half4*)v)[t] = h;
    }
}

// ---------------------------------------------------------------------------
// v-space propagate (all edge weights == 1), fp16 storage / fp32 accumulate:
//   vout[n][lane] = dinv[n]^2 * ( v[n][lane] + sum_{e->n} v[srcs[e]][lane] )
// One wave per node, lane = dim. beg/end wave-uniform (readfirstlane) so
// srcs[j] loads scalarize; 128 B gather per edge; 8 independent accumulators.
// ---------------------------------------------------------------------------
__launch_bounds__(256)
__global__ void spmv_v_kernel(const int* __restrict__ ptr,
                              const int* __restrict__ srcs,
                              const float* __restrict__ dinv,
                              const _Float16* __restrict__ v,
                              _Float16* __restrict__ vout, int N) {
    int wave = blockIdx.x * 4 + (threadIdx.x >> 6);
    int lane = threadIdx.x & 63;
    if (wave >= N) return;
    int beg = __builtin_amdgcn_readfirstlane(ptr[wave]);
    int end = __builtin_amdgcn_readfirstlane(ptr[wave + 1]);
    unsigned base = (unsigned)wave * DIM + (unsigned)lane;
    float a0 = (float)v[base];   // self-loop term
    float a1 = 0.f, a2 = 0.f, a3 = 0.f;
    float a4 = 0.f, a5 = 0.f, a6 = 0.f, a7 = 0.f;
    int j = beg;
    for (; j + 8 <= end; j += 8) {
        int s0 = srcs[j + 0], s1 = srcs[j + 1];
        int s2 = srcs[j + 2], s3 = srcs[j + 3];
        int s4 = srcs[j + 4], s5 = srcs[j + 5];
        int s6 = srcs[j + 6], s7 = srcs[j + 7];
        a0 += (float)v[(unsigned)s0 * DIM + (unsigned)lane];
        a1 += (float)v[(unsigned)s1 * DIM + (unsigned)lane];
        a2 += (float)v[(unsigned)s2 * DIM + (unsigned)lane];
        a3 += (float)v[(unsigned)s3 * DIM + (unsigned)lane];
        a4 += (float)v[(unsigned)s4 * DIM + (unsigned)lane];
        a5 += (float)v[(unsigned)s5 * DIM + (unsigned)lane];
        a6 += (float)v[(unsigned)s6 * DIM + (unsigned)lane];
        a7 += (float)v[(unsigned)s7 * DIM + (unsigned)lane];
    }
    if (j + 4 <= end) {
        int s0 = srcs[j + 0], s1 = srcs[j + 1];
        int s2 = srcs[j + 2], s3 = srcs[j + 3];
        a1 += (float)v[(unsigned)s0 * DIM + (unsigned)lane];
        a2 += (float)v[(unsigned)s1 * DIM + (unsigned)lane];
        a3 += (float)v[(unsigned)s2 * DIM + (unsigned)lane];
        a4 += (float)v[(unsigned)s3 * DIM + (unsigned)lane];
        j += 4;
    }
    for (; j < end; ++j)
        a0 += (float)v[(unsigned)srcs[j] * DIM + (unsigned)lane];
    float d = dinv[wave];
    float sum = ((a0 + a1) + (a2 + a3)) + ((a4 + a5) + (a6 + a7));
    vout[base] = (_Float16)(d * d * sum);
}

// ---------------------------------------------------------------------------
// Reference quirk: r never updates -> powers cumulative:
//   x_agg[1] = A x, x_agg[2] = A^3 x, x_agg[4] = A^7 x.
//   cat@W = x@W3 + p1@(W0-W3+W4) + p3@(W1-W4+W5) + p7@(W2-W5)
// weff layout: [src][k][d] flattened = [kk][d] with kk = src*64+k
// ---------------------------------------------------------------------------
__global__ void make_weff_kernel(const float* __restrict__ W,
                                 float* __restrict__ weff) {
    int t = blockIdx.x * blockDim.x + threadIdx.x;
    if (t < 64 * 64) {
        int k = t >> 6, d = t & 63;
        float w0 = W[(0 * 64 + k) * 64 + d];
        float w1 = W[(1 * 64 + k) * 64 + d];
        float w2 = W[(2 * 64 + k) * 64 + d];
        float w3 = W[(3 * 64 + k) * 64 + d];
        float w4 = W[(4 * 64 + k) * 64 + d];
        float w5 = W[(5 * 64 + k) * 64 + d];
        weff[(0 * 64 + k) * 64 + d] = w3;
        weff[(1 * 64 + k) * 64 + d] = w0 - w3 + w4;
        weff[(2 * 64 + k) * 64 + d] = w1 - w4 + w5;
        weff[(3 * 64 + k) * 64 + d] = w2 - w5;
    }
}

// ---------------------------------------------------------------------------
// MFMA combine (f16): out[16-node tile][64 dims] via mfma_f32_16x16x32_f16.
// Wave w owns dim slice [16w,16w+16). K=256 (4 src x 64) in 8 mfma steps.
// Verified layouts (m89/m91, dtype-indep): A m=lane&15,k=quad*8+j;
// B n=lane&15,k=quad*8+j; D col=lane&15,row=quad*4+reg.
// LDS rows padded to 264 halves: stride 132 dwords -> 2-way aliasing (free).
// ---------------------------------------------------------------------------
__launch_bounds__(256)
__global__ void combine_mfma_kernel(const float* __restrict__ x,
                                    const _Float16* __restrict__ v1,
                                    const _Float16* __restrict__ v3,
                                    const _Float16* __restrict__ v7,
                                    const float* __restrict__ rdinv,
                                    const float* __restrict__ weff,
                                    const float* __restrict__ bias,
                                    float* __restrict__ out, int N) {
    __shared__ _Float16 sWt[64][264];  // [dim][kk] transposed f16 W
    __shared__ _Float16 sA[16][264];   // [node][kk] f16 inputs

    int tid = threadIdx.x;
    // stage transposed f16 weights once per block
    for (int i = tid; i < 64 * 256; i += 256) {
        int kk = i >> 6, d = i & 63;
        sWt[d][kk] = (_Float16)weff[i];
    }
    int lane = tid & 63;
    int w = tid >> 6;            // wave id -> dim slice
    int quad = lane >> 4;
    int col = lane & 15;
    int dim = w * 16 + col;
    float bv = bias[dim];

    int ngroups = (N + 15) / 16;
    for (int g = blockIdx.x; g < ngroups; g += gridDim.x) {
        int n0 = g * 16;
        __syncthreads();
        // stage 16 nodes x 4 src x 64 dims -> f16 (rdinv un-scale for v*)
        for (int i = tid; i < 1024; i += 256) {
            int node = i >> 6;
            int rem = i & 63;
            int src = rem >> 4;
            int f = rem & 15;
            int n = n0 + node;
            half4 hq = {(_Float16)0.f, (_Float16)0.f,
                        (_Float16)0.f, (_Float16)0.f};
            if (n < N) {
                if (src == 0) {
                    float4 val = *(const float4*)(x + (size_t)n * DIM + f * 4);
                    hq.x = (_Float16)val.x; hq.y = (_Float16)val.y;
                    hq.z = (_Float16)val.z; hq.w = (_Float16)val.w;
                } else {
                    const _Float16* p = (src == 1) ? v1 : (src == 2) ? v3 : v7;
                    half4 hv = *(const half4*)(p + (size_t)n * DIM + f * 4);
                    float rd = rdinv[n];
                    hq.x = (_Float16)((float)hv.x * rd);
                    hq.y = (_Float16)((float)hv.y * rd);
                    hq.z = (_Float16)((float)hv.z * rd);
                    hq.w = (_Float16)((float)hv.w * rd);
                }
            }
            *(half4*)&sA[node][src * 64 + f * 4] = hq;
        }
        __syncthreads();

        floatx4 acc = {0.f, 0.f, 0.f, 0.f};
        #pragma unroll
        for (int t = 0; t < 8; ++t) {
            int k0 = t * 32 + quad * 8;
            half8 af = *(const half8*)&sA[col][k0];
            half8 bf = *(const half8*)&sWt[dim][k0];
            acc = __builtin_amdgcn_mfma_f32_16x16x32_f16(af, bf, acc, 0, 0, 0);
        }
        #pragma unroll
        for (int r = 0; r < 4; ++r) {
            int n = n0 + quad * 4 + r;
            if (n < N) {
                float vv = acc[r] + bv;
                out[(size_t)n * DIM + dim] = fmaxf(vv, 0.f);
            }
        }
    }
}

extern "C" void kernel_launch(void* const* d_in, const int* in_sizes, int n_in,
                              void* d_out, int out_size, void* d_ws, size_t ws_size,
                              hipStream_t stream) {
    const float* x  = (const float*)d_in[0];
    const int*   ei = (const int*)d_in[1];
    const float* W  = (const float*)d_in[2];
    const float* b  = (const float*)d_in[3];
    float* out = (float*)d_out;

    const int N = in_sizes[0] / DIM;
    const int E = in_sizes[1] / 2;
    const int* row = ei;
    const int* col = ei + E;

    const size_t ND = (size_t)N * DIM;
    float* ws = (float*)d_ws;
    float* dinv  = ws;                  // N floats
    float* rdinv = dinv + N;            // N floats
    float* weff  = rdinv + N;           // 4*64*64 = 16384 floats
    _Float16* v1 = (_Float16*)(weff + 4 * 64 * 64);  // ND halves (FIX: was +4096)
    _Float16* v3 = v1 + ND;             // ND halves
    _Float16* v7 = v3 + ND;             // ND halves
    _Float16* tA = v7 + ND;             // ND halves
    int*   deg   = (int*)(tA + ND);     // N
    int*   ptr   = deg + N;             // N+1
    int*   cur   = ptr + N + 1;         // N
    int*   bs    = cur + N;             // <=1024
    int*   srcs  = bs + 1024;           // E

    const int nb = (N + 255) / 256;

    // --- degree + dinv/rdinv ---
    hipMemsetAsync(deg, 0, (size_t)N * sizeof(int), stream);
    hipMemsetAsync(cur, 0, (size_t)N * sizeof(int), stream);
    count_deg_kernel<<<(E + 255) / 256, 256, 0, stream>>>(col, deg, E);
    dinv_kernel<<<nb, 256, 0, stream>>>(deg, dinv, rdinv, N);

    // --- exclusive scan deg -> ptr ---
    reduce_chunks_kernel<<<nb, 256, 0, stream>>>(deg, bs, N);
    scan_block_sums_kernel<<<1, 1024, 0, stream>>>(bs, nb);
    scan_chunks_kernel<<<nb, 256, 0, stream>>>(deg, bs, ptr, N);

    // --- CSC fill ---
    fill_csc_kernel<<<(E + 255) / 256, 256, 0, stream>>>(row, col, ptr, cur,
                                                         srcs, E);

    // --- effective W ---
    make_weff_kernel<<<16, 256, 0, stream>>>(W, weff);

    const int initGrid = (N * (DIM / 4) + 255) / 256;
    const int propGrid = (N + 3) / 4;   // 4 nodes (waves) per 256-thread block
    auto prop = [&](const _Float16* src, _Float16* dst) {
        spmv_v_kernel<<<propGrid, 256, 0, stream>>>(ptr, srcs, dinv, src, dst, N);
    };

    // v0 = dinv * x  (in tA)
    scale_init_kernel<<<initGrid, 256, 0, stream>>>(x, dinv, tA, N);
    prop(tA, v1);   // v1
    prop(v1, tA);   // v2
    prop(tA, v3);   // v3
    prop(v3, tA);   // v4
    prop(tA, v7);   // v5 (v7 as scratch)
    prop(v7, tA);   // v6
    prop(tA, v7);   // v7

    // --- combine (MFMA f16) ---
    combine_mfma_kernel<<<1024, 256, 0, stream>>>(x, v1, v3, v7, rdinv, weff,
                                                  b, out, N);
}

// Round 8
// 605.114 us; speedup vs baseline: 15.3713x; 1.0185x over previous
//
#include <hip/hip_runtime.h>

#define DIM 64

typedef __attribute__((ext_vector_type(8))) _Float16 half8;
typedef __attribute__((ext_vector_type(4))) _Float16 half4;
typedef __attribute__((ext_vector_type(4))) float floatx4;

// ---------------------------------------------------------------------------
// deg[col[e]] += 1  (int atomics, one-time CSC build)
// ---------------------------------------------------------------------------
__global__ void count_deg_kernel(const int* __restrict__ col,
                                 int* __restrict__ deg, int E) {
    int e = blockIdx.x * blockDim.x + threadIdx.x;
    if (e < E) atomicAdd(&deg[col[e]], 1);
}

// dinv[i] = rsqrt(deg+1), rdinv[i] = sqrt(deg+1)
__global__ void dinv_kernel(const int* __restrict__ deg,
                            float* __restrict__ dinv,
                            float* __restrict__ rdinv, int N) {
    int i = blockIdx.x * blockDim.x + threadIdx.x;
    if (i < N) {
        float d = (float)deg[i] + 1.0f;
        dinv[i] = rsqrtf(d);
        rdinv[i] = sqrtf(d);
    }
}

// --------------------------- exclusive scan over PADDED degree -------------
// pdeg = (deg+3)&~3 so every CSC bucket is a multiple of 4 edges.
__global__ void reduce_chunks_kernel(const int* __restrict__ deg,
                                     int* __restrict__ bs, int N) {
    __shared__ int s[256];
    int t = threadIdx.x;
    int i = blockIdx.x * 256 + t;
    s[t] = (i < N) ? ((deg[i] + 3) & ~3) : 0;
    __syncthreads();
    for (int d = 128; d > 0; d >>= 1) {
        if (t < d) s[t] += s[t + d];
        __syncthreads();
    }
    if (t == 0) bs[blockIdx.x] = s[0];
}

__global__ void scan_block_sums_kernel(int* __restrict__ bs, int nb) {
    __shared__ int s[1024];
    int t = threadIdx.x;
    s[t] = (t < nb) ? bs[t] : 0;
    __syncthreads();
    for (int d = 1; d < 1024; d <<= 1) {
        int v = (t >= d) ? s[t - d] : 0;
        __syncthreads();
        s[t] += v;
        __syncthreads();
    }
    if (t < nb) bs[t] = (t == 0) ? 0 : s[t - 1];
}

__global__ void scan_chunks_kernel(const int* __restrict__ deg,
                                   const int* __restrict__ bs,
                                   int* __restrict__ ptr, int N) {
    __shared__ int s[256];
    int b = blockIdx.x, t = threadIdx.x;
    int i = b * 256 + t;
    int v = (i < N) ? ((deg[i] + 3) & ~3) : 0;
    s[t] = v;
    __syncthreads();
    for (int d = 1; d < 256; d <<= 1) {
        int u = (t >= d) ? s[t - d] : 0;
        __syncthreads();
        s[t] += u;
        __syncthreads();
    }
    if (i < N) {
        int p = bs[b] + s[t] - v;
        ptr[i] = p;
        if (i == N - 1) ptr[N] = p + v;
    }
}

// pre-fill srcs with dummy node N (pad slots gather the zero row)
__global__ void prefill_srcs_kernel(int* __restrict__ srcs, int n, int val) {
    int i = blockIdx.x * blockDim.x + threadIdx.x;
    if (i < n) srcs[i] = val;
}

// fill CSC buckets: srcs grouped by destination node (padded layout)
__global__ void fill_csc_kernel(const int* __restrict__ row,
                                const int* __restrict__ col,
                                const int* __restrict__ ptr,
                                int* __restrict__ cursor,
                                int* __restrict__ srcs, int E) {
    int e = blockIdx.x * blockDim.x + threadIdx.x;
    if (e < E) {
        int c = col[e];
        int pos = ptr[c] + atomicAdd(&cursor[c], 1);
        srcs[pos] = row[e];
    }
}

// v0 = dinv * x  (fp32 -> fp16 v-space), one thread per 4 dims
__global__ void scale_init_kernel(const float* __restrict__ x,
                                  const float* __restrict__ dinv,
                                  _Float16* __restrict__ v, int N) {
    int t = blockIdx.x * blockDim.x + threadIdx.x;
    if (t < N * (DIM / 4)) {
        int n = t >> 4;
        float d = dinv[n];
        float4 a = ((const float4*)x)[t];
        half4 h;
        h.x = (_Float16)(a.x * d);
        h.y = (_Float16)(a.y * d);
        h.z = (_Float16)(a.z * d);
        h.w = (_Float16)(a.w * d);
        ((half4*)v)[t] = h;
    }
}

// zero dummy row N of all 4 v-buffers (padded CSC edges point here)
__global__ void zero_dummy_kernel(_Float16* v1, _Float16* v3, _Float16* v7,
                                  _Float16* tA, int N) {
    int t = threadIdx.x;
    if (t < DIM) {
        size_t o = (size_t)N * DIM + t;
        v1[o] = (_Float16)0.f;
        v3[o] = (_Float16)0.f;
        v7[o] = (_Float16)0.f;
        tA[o] = (_Float16)0.f;
    }
}

// ---------------------------------------------------------------------------
// v-space propagate (all edge weights == 1), fp16 storage / fp32 accumulate:
//   vout[n][:] = dinv[n]^2 * ( v[n][:] + sum_{e->n} v[srcs[e]][:] )
// One wave per node; 16 lanes per source row (half4 = 8 B/lane); 4 edges per
// gather instruction. Buckets padded to x4 (dummy -> zero row) = no tails.
// Cross-group reduction: shfl_xor 16/32. Lanes 0-15 write the row.
// ---------------------------------------------------------------------------
__launch_bounds__(256)
__global__ void spmv_v_kernel(const int* __restrict__ ptr,
                              const int* __restrict__ srcs,
                              const float* __restrict__ dinv,
                              const _Float16* __restrict__ v,
                              _Float16* __restrict__ vout, int N) {
    int wave = blockIdx.x * 4 + (threadIdx.x >> 6);
    int lane = threadIdx.x & 63;
    if (wave >= N) return;
    int beg = __builtin_amdgcn_readfirstlane(ptr[wave]);
    int end = __builtin_amdgcn_readfirstlane(ptr[wave + 1]);
    int grp = lane >> 4;          // edge slot 0..3
    int sub = lane & 15;          // dim quad
    float a0 = 0.f, a1 = 0.f, a2 = 0.f, a3 = 0.f;
    #pragma unroll 4
    for (int j = beg; j < end; j += 4) {
        int s = srcs[j + grp];                       // broadcast within group
        half4 hv = *(const half4*)(v + (unsigned)s * DIM + sub * 4);
        a0 += (float)hv.x;
        a1 += (float)hv.y;
        a2 += (float)hv.z;
        a3 += (float)hv.w;
    }
    // fold the 4 edge groups
    a0 += __shfl_xor(a0, 16); a1 += __shfl_xor(a1, 16);
    a2 += __shfl_xor(a2, 16); a3 += __shfl_xor(a3, 16);
    a0 += __shfl_xor(a0, 32); a1 += __shfl_xor(a1, 32);
    a2 += __shfl_xor(a2, 32); a3 += __shfl_xor(a3, 32);
    if (grp == 0) {
        half4 hs = *(const half4*)(v + (unsigned)wave * DIM + sub * 4);
        float d = dinv[wave];
        float dd = d * d;
        half4 r;
        r.x = (_Float16)(dd * (a0 + (float)hs.x));
        r.y = (_Float16)(dd * (a1 + (float)hs.y));
        r.z = (_Float16)(dd * (a2 + (float)hs.z));
        r.w = (_Float16)(dd * (a3 + (float)hs.w));
        *(half4*)(vout + (unsigned)wave * DIM + sub * 4) = r;
    }
}

// ---------------------------------------------------------------------------
// Reference quirk: r never updates -> powers cumulative:
//   x_agg[1] = A x, x_agg[2] = A^3 x, x_agg[4] = A^7 x.
//   cat@W = x@W3 + p1@(W0-W3+W4) + p3@(W1-W4+W5) + p7@(W2-W5)
// weff layout: [src][k][d] flattened = [kk][d] with kk = src*64+k
// ---------------------------------------------------------------------------
__global__ void make_weff_kernel(const float* __restrict__ W,
                                 float* __restrict__ weff) {
    int t = blockIdx.x * blockDim.x + threadIdx.x;
    if (t < 64 * 64) {
        int k = t >> 6, d = t & 63;
        float w0 = W[(0 * 64 + k) * 64 + d];
        float w1 = W[(1 * 64 + k) * 64 + d];
        float w2 = W[(2 * 64 + k) * 64 + d];
        float w3 = W[(3 * 64 + k) * 64 + d];
        float w4 = W[(4 * 64 + k) * 64 + d];
        float w5 = W[(5 * 64 + k) * 64 + d];
        weff[(0 * 64 + k) * 64 + d] = w3;
        weff[(1 * 64 + k) * 64 + d] = w0 - w3 + w4;
        weff[(2 * 64 + k) * 64 + d] = w1 - w4 + w5;
        weff[(3 * 64 + k) * 64 + d] = w2 - w5;
    }
}

// ---------------------------------------------------------------------------
// MFMA combine (f16): out[16-node tile][64 dims] via mfma_f32_16x16x32_f16.
// Verified layouts (m89/m91, dtype-indep): A m=lane&15,k=quad*8+j;
// B n=lane&15,k=quad*8+j; D col=lane&15,row=quad*4+reg.
// ---------------------------------------------------------------------------
__launch_bounds__(256)
__global__ void combine_mfma_kernel(const float* __restrict__ x,
                                    const _Float16* __restrict__ v1,
                                    const _Float16* __restrict__ v3,
                                    const _Float16* __restrict__ v7,
                                    const float* __restrict__ rdinv,
                                    const float* __restrict__ weff,
                                    const float* __restrict__ bias,
                                    float* __restrict__ out, int N) {
    __shared__ _Float16 sWt[64][264];  // [dim][kk] transposed f16 W
    __shared__ _Float16 sA[16][264];   // [node][kk] f16 inputs

    int tid = threadIdx.x;
    for (int i = tid; i < 64 * 256; i += 256) {
        int kk = i >> 6, d = i & 63;
        sWt[d][kk] = (_Float16)weff[i];
    }
    int lane = tid & 63;
    int w = tid >> 6;
    int quad = lane >> 4;
    int col = lane & 15;
    int dim = w * 16 + col;
    float bv = bias[dim];

    int ngroups = (N + 15) / 16;
    for (int g = blockIdx.x; g < ngroups; g += gridDim.x) {
        int n0 = g * 16;
        __syncthreads();
        for (int i = tid; i < 1024; i += 256) {
            int node = i >> 6;
            int rem = i & 63;
            int src = rem >> 4;
            int f = rem & 15;
            int n = n0 + node;
            half4 hq = {(_Float16)0.f, (_Float16)0.f,
                        (_Float16)0.f, (_Float16)0.f};
            if (n < N) {
                if (src == 0) {
                    float4 val = *(const float4*)(x + (size_t)n * DIM + f * 4);
                    hq.x = (_Float16)val.x; hq.y = (_Float16)val.y;
                    hq.z = (_Float16)val.z; hq.w = (_Float16)val.w;
                } else {
                    const _Float16* p = (src == 1) ? v1 : (src == 2) ? v3 : v7;
                    half4 hv = *(const half4*)(p + (size_t)n * DIM + f * 4);
                    float rd = rdinv[n];
                    hq.x = (_Float16)((float)hv.x * rd);
                    hq.y = (_Float16)((float)hv.y * rd);
                    hq.z = (_Float16)((float)hv.z * rd);
                    hq.w = (_Float16)((float)hv.w * rd);
                }
            }
            *(half4*)&sA[node][src * 64 + f * 4] = hq;
        }
        __syncthreads();

        floatx4 acc = {0.f, 0.f, 0.f, 0.f};
        #pragma unroll
        for (int t = 0; t < 8; ++t) {
            int k0 = t * 32 + quad * 8;
            half8 af = *(const half8*)&sA[col][k0];
            half8 bf = *(const half8*)&sWt[dim][k0];
            acc = __builtin_amdgcn_mfma_f32_16x16x32_f16(af, bf, acc, 0, 0, 0);
        }
        #pragma unroll
        for (int r = 0; r < 4; ++r) {
            int n = n0 + quad * 4 + r;
            if (n < N) {
                float vv = acc[r] + bv;
                out[(size_t)n * DIM + dim] = fmaxf(vv, 0.f);
            }
        }
    }
}

extern "C" void kernel_launch(void* const* d_in, const int* in_sizes, int n_in,
                              void* d_out, int out_size, void* d_ws, size_t ws_size,
                              hipStream_t stream) {
    const float* x  = (const float*)d_in[0];
    const int*   ei = (const int*)d_in[1];
    const float* W  = (const float*)d_in[2];
    const float* b  = (const float*)d_in[3];
    float* out = (float*)d_out;

    const int N = in_sizes[0] / DIM;
    const int E = in_sizes[1] / 2;
    const int* row = ei;
    const int* col = ei + E;

    const size_t NDH = (size_t)(N + 1) * DIM;   // +1 dummy zero row
    const int Epad = E + 3 * N;                 // upper bound on padded edges
    float* ws = (float*)d_ws;
    float* dinv  = ws;                  // N floats
    float* rdinv = dinv + N;            // N floats
    float* weff  = rdinv + N;           // 4*64*64 = 16384 floats
    _Float16* v1 = (_Float16*)(weff + 4 * 64 * 64);  // NDH halves
    _Float16* v3 = v1 + NDH;            // NDH halves
    _Float16* v7 = v3 + NDH;            // NDH halves
    _Float16* tA = v7 + NDH;            // NDH halves
    int*   deg   = (int*)(tA + NDH);    // N
    int*   ptr   = deg + N;             // N+1
    int*   cur   = ptr + N + 1;         // N
    int*   bs    = cur + N;             // <=1024
    int*   srcs  = bs + 1024;           // Epad

    const int nb = (N + 255) / 256;

    // --- degree + dinv/rdinv ---
    hipMemsetAsync(deg, 0, (size_t)N * sizeof(int), stream);
    hipMemsetAsync(cur, 0, (size_t)N * sizeof(int), stream);
    count_deg_kernel<<<(E + 255) / 256, 256, 0, stream>>>(col, deg, E);
    dinv_kernel<<<nb, 256, 0, stream>>>(deg, dinv, rdinv, N);

    // --- exclusive scan of padded deg -> ptr ---
    reduce_chunks_kernel<<<nb, 256, 0, stream>>>(deg, bs, N);
    scan_block_sums_kernel<<<1, 1024, 0, stream>>>(bs, nb);
    scan_chunks_kernel<<<nb, 256, 0, stream>>>(deg, bs, ptr, N);

    // --- CSC fill (pad slots stay = N) ---
    prefill_srcs_kernel<<<(Epad + 255) / 256, 256, 0, stream>>>(srcs, Epad, N);
    fill_csc_kernel<<<(E + 255) / 256, 256, 0, stream>>>(row, col, ptr, cur,
                                                         srcs, E);

    // --- effective W ---
    make_weff_kernel<<<16, 256, 0, stream>>>(W, weff);

    const int initGrid = (N * (DIM / 4) + 255) / 256;
    const int propGrid = (N + 3) / 4;   // 4 nodes (waves) per 256-thread block
    auto prop = [&](const _Float16* src, _Float16* dst) {
        spmv_v_kernel<<<propGrid, 256, 0, stream>>>(ptr, srcs, dinv, src, dst, N);
    };

    // v0 = dinv * x (in tA); zero dummy rows
    scale_init_kernel<<<initGrid, 256, 0, stream>>>(x, dinv, tA, N);
    zero_dummy_kernel<<<1, 64, 0, stream>>>(v1, v3, v7, tA, N);

    prop(tA, v1);   // v1
    prop(v1, tA);   // v2
    prop(tA, v3);   // v3
    prop(v3, tA);   // v4
    prop(tA, v7);   // v5 (v7 as scratch)
    prop(v7, tA);   // v6
    prop(tA, v7);   // v7

    // --- combine (MFMA f16) ---
    combine_mfma_kernel<<<1024, 256, 0, stream>>>(x, v1, v3, v7, rdinv, weff,
                                                  b, out, N);
}